// Round 4
// baseline (80.261 us; speedup 1.0000x reference)
//
#include <hip/hip_runtime.h>
#include <hip/hip_bf16.h>

// Problem constants (from reference)
constexpr int S = 256;          // N_SINES
constexpr int N = 512;          // control points
constexpr int R = 32;           // RESAMPLING_FACTOR
constexpr int OUT_N = N * R;    // 16384 output samples per batch
constexpr int ROWS = N + 1;     // 513 packed param rows per batch (row 0 = head)

// ---------------------------------------------------------------------------
// Kernel 1 (prep): per-(b,s) fp64 block-prefix scan + packed param rows.
//
// G(n) = 16*f0 + sum_{m<n} 16*(f_m + f_{m+1})  — exact closed form of the
// reference's f32 cumsum at upsample-block boundaries (Hz-samples; the
// 2*pi/FS cancels since frac(phase/2pi) = frac(G/44100)). fp64 scan is
// required: G reaches ~8e7, f32 would destroy the fractional phase.
//
// Packed rows, layout [b][row][s] (s contiguous so synth's s-loop streams):
//   row 0     = {0,            f_0,   0,     a_0,   0}    (head clip region)
//   row n+1   = {frac(G(n)/FS), f_n,  df_n,  a_n,  da_n}  (n = 0..511)
//   row 512 doubles as the tail row (df=da=0 from clamping).
// With these rows, EVERY output sample uses one formula:
//   r(rev) = gfrac + c1*f + c2*df ;  amp = a + wa*da
// ---------------------------------------------------------------------------
__global__ __launch_bounds__(512) void prep_kernel(
    const float* __restrict__ freq, const float* __restrict__ amp,
    float4* __restrict__ P4, float* __restrict__ P1) {
  const int row = blockIdx.x;          // b*S + s
  const int n = threadIdx.x;           // 0..511
  const int b = row / S;
  const int s = row - b * S;
  const float* f = freq + (size_t)row * N;
  const float* a = amp  + (size_t)row * N;

  const float fn  = f[n];
  const float fn1 = (n < N - 1) ? f[n + 1] : fn;   // clamped
  const float an  = a[n];
  const float an1 = (n < N - 1) ? a[n + 1] : an;

  __shared__ double sh[N];
  sh[n] = (n < N - 1) ? 16.0 * ((double)fn + (double)fn1) : 0.0;
  __syncthreads();

  for (int off = 1; off < N; off <<= 1) {
    double add = (n >= off) ? sh[n - off] : 0.0;
    __syncthreads();
    sh[n] += add;
    __syncthreads();
  }

  const double G = 16.0 * (double)f[0] + ((n == 0) ? 0.0 : sh[n - 1]);
  double q = G * (1.0 / 44100.0);      // revolutions
  q -= floor(q);                       // frac -> [0,1), exact to ~2e-13
  const float gfrac = (float)q;

  const size_t base = (size_t)b * ROWS;
  const size_t o = (base + (size_t)(n + 1)) * S + s;
  P4[o] = make_float4(gfrac, fn, fn1 - fn, an);
  P1[o] = an1 - an;
  if (n == 0) {                        // synthetic head row
    const size_t oh = base * S + s;
    P4[oh] = make_float4(0.0f, fn, 0.0f, an);
    P1[oh] = 0.0f;
  }
}

// ---------------------------------------------------------------------------
// Kernel 2 (synth): uniform all-f32 inner loop, 2 loads + 6 VALU per sine.
// Block = 64 consecutive output samples of one batch; 4 waves each cover 64
// of the 256 sines (s-contiguous float4 stream, ~15 KB/block L1-resident),
// then LDS-reduce 4 partials.
//
//   j <  16    : row 0,   c1 = j+1,          c2 = 0,           wa = 0
//   mid        : row n+1, c1 = k+1,          c2 = (k+1)^2/64,  wa = (k+.5)/32
//                (n=(j-16)>>5, k=(j-16)&31)
//   j >= 16368 : row 512, c1 = j-16367,      c2 = 0,           wa = 0
//   r = gfrac + (c1*f + c2*df)/FS ; out += (a + wa*da) * sin(2*pi*frac(r))
// ---------------------------------------------------------------------------
__global__ __launch_bounds__(256) void synth_kernel(
    const float4* __restrict__ P4, const float* __restrict__ P1,
    float* __restrict__ out) {
  const int tid = threadIdx.x;
  const int split = tid >> 6;                 // wave id 0..3 -> s-chunk
  const int samp = tid & 63;
  const int gid = blockIdx.x * 64 + samp;     // global output sample id
  const int b = gid >> 14;                    // / OUT_N
  const int j = gid & (OUT_N - 1);

  int row;
  float c1, c2, wa;
  if (j < 16) {                               // head clip region
    row = 0; c1 = (float)(j + 1); c2 = 0.0f; wa = 0.0f;
  } else if (j >= OUT_N - 16) {               // tail clip region
    row = N; c1 = (float)(j - (OUT_N - 16) + 1); c2 = 0.0f; wa = 0.0f;
  } else {
    const int jj = j - 16;
    const int k = jj & 31;
    row = (jj >> 5) + 1;
    c1 = (float)(k + 1);
    c2 = (float)((k + 1) * (k + 1)) * (1.0f / 64.0f);
    wa = ((float)k + 0.5f) * (1.0f / 32.0f);
  }
  const float inv_fs = 1.0f / 44100.0f;
  c1 *= inv_fs;                               // rev per Hz
  c2 *= inv_fs;

  const size_t base = ((size_t)b * ROWS + (size_t)row) * S;
  const float4* __restrict__ p4 = P4 + base;
  const float*  __restrict__ p1 = P1 + base;

  float acc = 0.0f;
  const int s0 = split * (S / 4);
  #pragma unroll 16
  for (int s = s0; s < s0 + S / 4; ++s) {
    const float4 v = p4[s];                   // {gfrac, f, df, a}
    const float da = p1[s];
    float r = fmaf(c2, v.z, fmaf(c1, v.y, v.x));
    r = __builtin_amdgcn_fractf(r);           // v_fract_f32 -> [0,1) rev
    const float sv = __builtin_amdgcn_sinf(r);// v_sin_f32: sin(2*pi*r)
    acc = fmaf(fmaf(da, wa, v.w), sv, acc);
  }

  __shared__ float red[256];
  red[tid] = acc;
  __syncthreads();
  if (tid < 64) {
    out[gid] = red[tid] + red[tid + 64] + red[tid + 128] + red[tid + 192];
  }
}

// ---------------------------------------------------------------------------
extern "C" void kernel_launch(void* const* d_in, const int* in_sizes, int n_in,
                              void* d_out, int out_size, void* d_ws, size_t ws_size,
                              hipStream_t stream) {
  const float* freq = (const float*)d_in[0];
  const float* amp  = (const float*)d_in[1];
  float* out = (float*)d_out;

  const int B = in_sizes[0] / (S * N);        // 4
  // Workspace: P4 [B*ROWS*S] float4 (~8.2 MiB), then P1 [B*ROWS*S] float
  float4* P4 = (float4*)d_ws;
  float*  P1 = (float*)((char*)d_ws + (size_t)B * ROWS * S * sizeof(float4));

  prep_kernel<<<dim3(B * S), dim3(512), 0, stream>>>(freq, amp, P4, P1);
  synth_kernel<<<dim3(B * OUT_N / 64), dim3(256), 0, stream>>>(P4, P1, out);
}